// Round 1
// baseline (4452.729 us; speedup 1.0000x reference)
//
#include <hip/hip_runtime.h>
#include <cmath>

#define BATCH 8
#define CHN 256
#define HH 128
#define WW 128
#define HWSZ (HH*WW)
#define NCLS 81
#define NFG 80
#define KTOP 100
#define EPSV 1e-6f
#define TILE 32
#define ICCH 16

// ---------------------------------------------------------------------------
// Kernel 1: conv3x3(C->C)+bias+ReLU fused with conv1x1(C->81)+bias, softmax,
// foreground argmax. Block = 256 threads (one per out-channel) x 32-pixel row
// tile. Writes logits to d_out, (cls, prob) per-pixel maps to ws.
// ---------------------------------------------------------------------------
__global__ __launch_bounds__(256) void fused_conv_kernel(
    const float* __restrict__ x, const float* __restrict__ w1,
    const float* __restrict__ b1, const float* __restrict__ w2,
    const float* __restrict__ b2, float* __restrict__ logits_out,
    int* __restrict__ cls_map, float* __restrict__ prob_map)
{
    __shared__ float xs[ICCH][3][36];   // x tile, rows padded to 36 (16B align)
    __shared__ float ys[CHN][36];       // relu(conv1) tile [oc][px], pad 36
    __shared__ float ls[NCLS][36];      // logits tile [cls][px]

    const int blk = blockIdx.x;         // B*H*(W/32) = 4096
    const int b   = blk >> 9;           // 512 blocks per batch
    const int rem = blk & 511;
    const int h   = rem >> 2;
    const int w0  = (rem & 3) << 5;
    const int t   = threadIdx.x;
    const int oc  = t;

    float acc[TILE];
#pragma unroll
    for (int i = 0; i < TILE; ++i) acc[i] = 0.f;

    const float* xb = x + (size_t)b * CHN * HWSZ;

    for (int icc = 0; icc < CHN; icc += ICCH) {
        __syncthreads();
        // stage x tile: 16 ic x 3 rows x 34 cols, zero-padded at borders
        for (int li = t; li < ICCH * 3 * 34; li += 256) {
            int ic  = li / 102;         // 102 = 3*34
            int r   = (li % 102) / 34;
            int col = li % 34;          // ok: 34 | 102
            int gh = h - 1 + r;
            int gw = w0 - 1 + col;
            float v = 0.f;
            if ((unsigned)gh < HH && (unsigned)gw < WW)
                v = xb[(size_t)(icc + ic) * HWSZ + gh * WW + gw];
            xs[ic][r][col] = v;
        }
        __syncthreads();

        const float* wp = w1 + (size_t)oc * (CHN * 9) + (size_t)icc * 9;
#pragma unroll 2
        for (int ic = 0; ic < ICCH; ++ic) {
            float wk[9];
#pragma unroll
            for (int k = 0; k < 9; ++k) wk[k] = wp[ic * 9 + k];
#pragma unroll
            for (int kh = 0; kh < 3; ++kh) {
                float xr[34];
#pragma unroll
                for (int j = 0; j < 34; ++j) xr[j] = xs[ic][kh][j];
#pragma unroll
                for (int kw = 0; kw < 3; ++kw) {
                    float wv = wk[kh * 3 + kw];
#pragma unroll
                    for (int px = 0; px < TILE; ++px)
                        acc[px] = fmaf(wv, xr[px + kw], acc[px]);
                }
            }
        }
    }

    // bias + relu -> LDS
    float bias = b1[oc];
#pragma unroll
    for (int px = 0; px < TILE; ++px) {
        float v = acc[px] + bias;
        ys[oc][px] = v > 0.f ? v : 0.f;
    }
    __syncthreads();

    // 1x1 conv to 81 classes: 162 threads = 81 classes x 2 pixel-halves
    if (t < 2 * NCLS) {
        int c   = t % NCLS;
        int ph  = t / NCLS;
        int pxo = ph * 16;
        float acc2[16];
        float bias2 = b2[c];
#pragma unroll
        for (int i = 0; i < 16; ++i) acc2[i] = bias2;
        const float* w2p = w2 + c * CHN;
#pragma unroll 4
        for (int ic = 0; ic < CHN; ++ic) {
            float wv = w2p[ic];
#pragma unroll
            for (int i = 0; i < 16; ++i)
                acc2[i] = fmaf(wv, ys[ic][pxo + i], acc2[i]);
        }
        float* lo = logits_out + ((size_t)b * NCLS + c) * HWSZ + h * WW + w0 + pxo;
#pragma unroll
        for (int i = 0; i < 16; ++i) { lo[i] = acc2[i]; ls[c][pxo + i] = acc2[i]; }
    }
    __syncthreads();

    // softmax + first-occurrence argmax over foreground classes
    if (t < TILE) {
        int px = t;
        float m = -1e30f;
#pragma unroll
        for (int c = 0; c < NCLS; ++c) m = fmaxf(m, ls[c][px]);
        float s = 0.f;
        for (int c = 0; c < NCLS; ++c) s += expf(ls[c][px] - m);
        float best = -1e30f; int bc = 0;
        for (int c = 0; c < NFG; ++c) {
            float v = ls[c][px];
            if (v > best) { best = v; bc = c; }   // strict > keeps first index
        }
        float prob = expf(best - m) / s;
        int off = b * HWSZ + h * WW + w0 + px;
        cls_map[off]  = bc;
        prob_map[off] = prob;
    }
}

// ---------------------------------------------------------------------------
// Kernel 2: masked 8-neighbor local-max boost -> score map.
// Masked channel value at neighbor is prob only if neighbor winner == my cls.
// ---------------------------------------------------------------------------
__global__ __launch_bounds__(256) void locmax_kernel(
    const int* __restrict__ cls_map, const float* __restrict__ prob_map,
    float* __restrict__ score)
{
    int i = blockIdx.x * 256 + threadIdx.x;   // exact grid: B*HW/256
    int b = i >> 14;
    int p = i & (HWSZ - 1);
    int h = p >> 7, w = p & 127;
    int mycls = cls_map[i];
    float myp = prob_map[i];
    bool lm = (myp >= EPSV);
#pragma unroll
    for (int dh = -1; dh <= 1; ++dh)
#pragma unroll
        for (int dw = -1; dw <= 1; ++dw) {
            if (dh == 0 && dw == 0) continue;
            int nh = h + dh, nw = w + dw;
            if ((unsigned)nh < HH && (unsigned)nw < WW) {
                int ni = b * HWSZ + nh * WW + nw;
                if (cls_map[ni] == mycls && myp < prob_map[ni]) lm = false;
            }
        }
    score[i] = myp + (lm ? 1.f : 0.f);
}

// ---------------------------------------------------------------------------
// Kernel 3: per-batch top-100, jax.lax.top_k semantics (value desc, tie ->
// lower index). Key = (float_bits << 32) | ~pix (scores strictly > 0).
// 100 extract-max rounds over per-thread cached segment maxima; only the
// owner thread rescans its 64-element segment (strided, coalesced layout).
// ---------------------------------------------------------------------------
__global__ __launch_bounds__(256) void topk_kernel(
    float* __restrict__ score, int* __restrict__ idx_out)
{
    __shared__ unsigned long long candl[256];
    __shared__ unsigned long long wmax[4];
    __shared__ unsigned long long bestsh;
    const int b = blockIdx.x;
    const int t = threadIdx.x;
    float* sc = score + b * HWSZ;

    unsigned long long lmax = 0;
    for (int i = 0; i < 64; ++i) {
        int p = t + (i << 8);                 // coalesced strided segments
        unsigned int fb = __float_as_uint(sc[p]);
        unsigned long long k =
            ((unsigned long long)fb << 32) | (unsigned int)(~p);
        if (k > lmax) lmax = k;
    }
    candl[t] = lmax;
    __syncthreads();

    for (int it = 0; it < KTOP; ++it) {
        unsigned long long v = candl[t];
#pragma unroll
        for (int off = 32; off > 0; off >>= 1) {
            unsigned long long o = __shfl_down(v, off);
            if (o > v) v = o;
        }
        if ((t & 63) == 0) wmax[t >> 6] = v;
        __syncthreads();
        if (t == 0) {
            unsigned long long bb = wmax[0];
            for (int wv = 1; wv < 4; ++wv) if (wmax[wv] > bb) bb = wmax[wv];
            bestsh = bb;
            int pix = (int)(~(unsigned int)(bb & 0xFFFFFFFFull)) & (HWSZ - 1);
            idx_out[b * KTOP + it] = pix;
        }
        __syncthreads();
        unsigned long long bb = bestsh;
        int pix = (int)(~(unsigned int)(bb & 0xFFFFFFFFull)) & (HWSZ - 1);
        int owner = pix & 255;
        if (t == owner) {
            sc[pix] = 0.f;                    // fb=0 -> never re-selected
            unsigned long long nm = 0;
            for (int i = 0; i < 64; ++i) {
                int p = t + (i << 8);
                unsigned int fb = __float_as_uint(sc[p]);
                unsigned long long k =
                    ((unsigned long long)fb << 32) | (unsigned int)(~p);
                if (k > nm) nm = k;
            }
            candl[t] = nm;
        }
        __syncthreads();
    }
}

// ---------------------------------------------------------------------------
// Kernel 4: gather x and pos_embeddings at top-k indices.
// out0[b][c][j] = x[b][c][idx], out1[b][c][j] = pos[0][c][idx]
// ---------------------------------------------------------------------------
__global__ __launch_bounds__(256) void gather_kernel(
    const float* __restrict__ x, const float* __restrict__ pos,
    const int* __restrict__ idx, float* __restrict__ out0,
    float* __restrict__ out1)
{
    int blk = blockIdx.x;                     // B*KTOP
    int b = blk / KTOP;
    int j = blk % KTOP;
    int c = threadIdx.x;
    int pix = idx[b * KTOP + j];
    out0[((size_t)b * CHN + c) * KTOP + j] = x[((size_t)b * CHN + c) * HWSZ + pix];
    out1[((size_t)b * CHN + c) * KTOP + j] = pos[(size_t)c * HWSZ + pix];
}

extern "C" void kernel_launch(void* const* d_in, const int* in_sizes, int n_in,
                              void* d_out, int out_size, void* d_ws, size_t ws_size,
                              hipStream_t stream) {
    (void)in_sizes; (void)n_in; (void)out_size; (void)ws_size;
    const float* x   = (const float*)d_in[0];
    const float* pos = (const float*)d_in[1];
    const float* w1  = (const float*)d_in[2];
    const float* b1  = (const float*)d_in[3];
    const float* w2  = (const float*)d_in[4];
    const float* b2  = (const float*)d_in[5];

    float* out0   = (float*)d_out;                    // [8,256,100]
    float* out1   = out0 + BATCH * CHN * KTOP;        // [8,256,100]
    float* logits = out1 + BATCH * CHN * KTOP;        // [8,81,128,128]

    char* ws = (char*)d_ws;
    int*   cls_map  = (int*)ws;                               // 512 KB
    float* prob_map = (float*)(ws + (size_t)BATCH * HWSZ * 4);        // 512 KB
    float* score    = (float*)(ws + (size_t)2 * BATCH * HWSZ * 4);    // 512 KB
    int*   idx      = (int*)(ws + (size_t)3 * BATCH * HWSZ * 4);      // 3.2 KB

    fused_conv_kernel<<<BATCH * HH * (WW / TILE), 256, 0, stream>>>(
        x, w1, b1, w2, b2, logits, cls_map, prob_map);
    locmax_kernel<<<(BATCH * HWSZ) / 256, 256, 0, stream>>>(
        cls_map, prob_map, score);
    topk_kernel<<<BATCH, 256, 0, stream>>>(score, idx);
    gather_kernel<<<BATCH * KTOP, 256, 0, stream>>>(x, pos, idx, out0, out1);
}

// Round 2
// 3149.894 us; speedup vs baseline: 1.4136x; 1.4136x over previous
//
#include <hip/hip_runtime.h>
#include <cmath>

#define BATCH 8
#define CHN 256
#define HH 128
#define WW 128
#define HWSZ (HH*WW)
#define NCLS 81
#define NFG 80
#define KTOP 100
#define EPSV 1e-6f
#define ICCH 32

// ===========================================================================
// Prep: transpose weights for coalesced access.
// w1t[(ic*9+k)*256 + oc] = w1[oc*2304 + ic*9 + k]
// w2t[ic*81 + c]         = w2[c*256 + ic]
// ===========================================================================
__global__ __launch_bounds__(256) void prep_weights(
    const float* __restrict__ w1, const float* __restrict__ w2,
    float* __restrict__ w1t, float* __restrict__ w2t)
{
    int i = blockIdx.x * 256 + threadIdx.x;
    if (i < 2304 * 256) {
        int ick = i >> 8;
        int oc  = i & 255;
        w1t[ick * 256 + oc] = w1[oc * 2304 + ick];
    } else {
        int j = i - 2304 * 256;
        if (j < 256 * 81) {
            int ic = j / 81, c = j - ic * 81;
            w2t[ic * 81 + c] = w2[c * 256 + ic];
        }
    }
}

// ===========================================================================
// Kernel A: conv3x3(256->256) + bias + relu  ->  y in NHWC [B*HW][256] (ws).
// Block = 256 threads = 4 waves; wave = one 16-pixel group; thread owns
// oc = {lane, lane+64, lane+128, lane+192} x 16 px.  x tile broadcast from
// LDS (wave-uniform ds_read_b128), weights coalesced from w1t.
// ===========================================================================
__global__ __launch_bounds__(256) void conv3_kernel(
    const float* __restrict__ x, const float* __restrict__ w1t,
    const float* __restrict__ b1, float* __restrict__ y)
{
    __shared__ float xs[ICCH][3][68];    // rows padded to 68 (272B, 16B mult)

    const int blk  = blockIdx.x;         // 2048 = 8 * 128 * 2
    const int b    = blk >> 8;
    const int h    = (blk >> 1) & 127;
    const int w0   = (blk & 1) << 6;     // 64-pixel row segment
    const int t    = threadIdx.x;
    const int lane = t & 63;
    const int pxg  = t >> 6;             // wave id = pixel group
    const int colbase = pxg << 4;

    float acc[4][16];
#pragma unroll
    for (int j = 0; j < 4; ++j)
#pragma unroll
        for (int p = 0; p < 16; ++p) acc[j][p] = 0.f;

    const float* xb = x + (size_t)b * CHN * HWSZ;

    for (int icc = 0; icc < CHN; icc += ICCH) {
        __syncthreads();
        // stage 32 ic x 3 rows x 66 cols (zero-padded halo)
        for (int li = t; li < ICCH * 3 * 66; li += 256) {
            int ic  = li / 198;
            int rr  = li - ic * 198;
            int r   = rr / 66;
            int col = rr - r * 66;
            int gh = h - 1 + r;
            int gw = w0 - 1 + col;
            float v = 0.f;
            if ((unsigned)gh < HH && (unsigned)gw < WW)
                v = xb[(size_t)(icc + ic) * HWSZ + gh * WW + gw];
            xs[ic][r][col] = v;
        }
        __syncthreads();

        for (int ic = 0; ic < ICCH; ++ic) {
            const float* wrow = w1t + (size_t)(icc + ic) * 9 * 256 + lane;
#pragma unroll
            for (int kh = 0; kh < 3; ++kh) {
                float xr[18];
#pragma unroll
                for (int u = 0; u < 18; ++u) xr[u] = xs[ic][kh][colbase + u];
#pragma unroll
                for (int j = 0; j < 4; ++j) {
                    float wv0 = wrow[(kh * 3 + 0) * 256 + j * 64];
                    float wv1 = wrow[(kh * 3 + 1) * 256 + j * 64];
                    float wv2 = wrow[(kh * 3 + 2) * 256 + j * 64];
#pragma unroll
                    for (int p = 0; p < 16; ++p) {
                        float a = acc[j][p];
                        a = fmaf(wv0, xr[p],     a);
                        a = fmaf(wv1, xr[p + 1], a);
                        a = fmaf(wv2, xr[p + 2], a);
                        acc[j][p] = a;
                    }
                }
            }
        }
    }

    // bias + relu -> y[pxflat][oc], coalesced stores
    size_t pxflat = (size_t)b * HWSZ + h * WW + w0 + colbase;
#pragma unroll
    for (int j = 0; j < 4; ++j) {
        float bias = b1[j * 64 + lane];
#pragma unroll
        for (int p = 0; p < 16; ++p) {
            float v = acc[j][p] + bias;
            y[(pxflat + p) * CHN + j * 64 + lane] = v > 0.f ? v : 0.f;
        }
    }
}

// ===========================================================================
// Kernel B: 1x1 conv (256->81) + bias + softmax + foreground argmax.
// Block = 32 pixels; threads t<162: (g = t/81 pixel-half, c = t%81 class).
// y reads are float4 broadcast (L2-hit); w2t reads coalesced over c.
// ===========================================================================
__global__ __launch_bounds__(256) void head_kernel(
    const float* __restrict__ y, const float* __restrict__ w2t,
    const float* __restrict__ b2, float* __restrict__ logits_out,
    int* __restrict__ cls_map, float* __restrict__ prob_map)
{
    __shared__ float ls[32][NCLS];
    const int blk = blockIdx.x;              // 4096 = 131072 / 32
    const int t   = threadIdx.x;
    const size_t px0 = (size_t)blk * 32;     // flat pixel base

    if (t < 2 * NCLS) {
        int g = t / NCLS;
        int c = t - g * NCLS;
        float acc[16];
        float bias = b2[c];
#pragma unroll
        for (int p = 0; p < 16; ++p) acc[p] = bias;
        const float* yb = y + (px0 + g * 16) * CHN;
        for (int ic4 = 0; ic4 < 64; ++ic4) {
            float wv[4];
#pragma unroll
            for (int u = 0; u < 4; ++u) wv[u] = w2t[(ic4 * 4 + u) * NCLS + c];
#pragma unroll
            for (int p = 0; p < 16; ++p) {
                const float4 yv = *(const float4*)(yb + (size_t)p * CHN + ic4 * 4);
                float a = acc[p];
                a = fmaf(wv[0], yv.x, a);
                a = fmaf(wv[1], yv.y, a);
                a = fmaf(wv[2], yv.z, a);
                a = fmaf(wv[3], yv.w, a);
                acc[p] = a;
            }
        }
        int bb = (int)(px0 >> 14);
        int hw = (int)(px0 & (HWSZ - 1)) + g * 16;
        float* lo = logits_out + ((size_t)bb * NCLS + c) * HWSZ + hw;
#pragma unroll
        for (int p = 0; p < 16; ++p) { lo[p] = acc[p]; ls[g * 16 + p][c] = acc[p]; }
    }
    __syncthreads();

    if (t < 32) {
        float m = -1e30f;
#pragma unroll
        for (int c = 0; c < NCLS; ++c) m = fmaxf(m, ls[t][c]);
        float s = 0.f;
        for (int c = 0; c < NCLS; ++c) s += expf(ls[t][c] - m);
        float best = -1e30f; int bc = 0;
        for (int c = 0; c < NFG; ++c) {
            float v = ls[t][c];
            if (v > best) { best = v; bc = c; }   // strict > keeps first index
        }
        cls_map[px0 + t]  = bc;
        prob_map[px0 + t] = expf(best - m) / s;
    }
}

// ===========================================================================
// Kernel: masked 8-neighbor local-max boost -> score map. (unchanged, passed)
// ===========================================================================
__global__ __launch_bounds__(256) void locmax_kernel(
    const int* __restrict__ cls_map, const float* __restrict__ prob_map,
    float* __restrict__ score)
{
    int i = blockIdx.x * 256 + threadIdx.x;
    int b = i >> 14;
    int p = i & (HWSZ - 1);
    int h = p >> 7, w = p & 127;
    int mycls = cls_map[i];
    float myp = prob_map[i];
    bool lm = (myp >= EPSV);
#pragma unroll
    for (int dh = -1; dh <= 1; ++dh)
#pragma unroll
        for (int dw = -1; dw <= 1; ++dw) {
            if (dh == 0 && dw == 0) continue;
            int nh = h + dh, nw = w + dw;
            if ((unsigned)nh < HH && (unsigned)nw < WW) {
                int ni = b * HWSZ + nh * WW + nw;
                if (cls_map[ni] == mycls && myp < prob_map[ni]) lm = false;
            }
        }
    score[i] = myp + (lm ? 1.f : 0.f);
}

// ===========================================================================
// Kernel: per-batch top-100, jax.lax.top_k semantics. (unchanged, passed)
// ===========================================================================
__global__ __launch_bounds__(256) void topk_kernel(
    float* __restrict__ score, int* __restrict__ idx_out)
{
    __shared__ unsigned long long candl[256];
    __shared__ unsigned long long wmax[4];
    __shared__ unsigned long long bestsh;
    const int b = blockIdx.x;
    const int t = threadIdx.x;
    float* sc = score + b * HWSZ;

    unsigned long long lmax = 0;
    for (int i = 0; i < 64; ++i) {
        int p = t + (i << 8);
        unsigned int fb = __float_as_uint(sc[p]);
        unsigned long long k =
            ((unsigned long long)fb << 32) | (unsigned int)(~p);
        if (k > lmax) lmax = k;
    }
    candl[t] = lmax;
    __syncthreads();

    for (int it = 0; it < KTOP; ++it) {
        unsigned long long v = candl[t];
#pragma unroll
        for (int off = 32; off > 0; off >>= 1) {
            unsigned long long o = __shfl_down(v, off);
            if (o > v) v = o;
        }
        if ((t & 63) == 0) wmax[t >> 6] = v;
        __syncthreads();
        if (t == 0) {
            unsigned long long bb = wmax[0];
            for (int wv = 1; wv < 4; ++wv) if (wmax[wv] > bb) bb = wmax[wv];
            bestsh = bb;
            int pix = (int)(~(unsigned int)(bb & 0xFFFFFFFFull)) & (HWSZ - 1);
            idx_out[b * KTOP + it] = pix;
        }
        __syncthreads();
        unsigned long long bb = bestsh;
        int pix = (int)(~(unsigned int)(bb & 0xFFFFFFFFull)) & (HWSZ - 1);
        int owner = pix & 255;
        if (t == owner) {
            sc[pix] = 0.f;
            unsigned long long nm = 0;
            for (int i = 0; i < 64; ++i) {
                int p = t + (i << 8);
                unsigned int fb = __float_as_uint(sc[p]);
                unsigned long long k =
                    ((unsigned long long)fb << 32) | (unsigned int)(~p);
                if (k > nm) nm = k;
            }
            candl[t] = nm;
        }
        __syncthreads();
    }
}

// ===========================================================================
// Kernel: gather x / pos_embeddings at top-k indices. (unchanged, passed)
// ===========================================================================
__global__ __launch_bounds__(256) void gather_kernel(
    const float* __restrict__ x, const float* __restrict__ pos,
    const int* __restrict__ idx, float* __restrict__ out0,
    float* __restrict__ out1)
{
    int blk = blockIdx.x;
    int b = blk / KTOP;
    int j = blk - b * KTOP;
    int c = threadIdx.x;
    int pix = idx[b * KTOP + j];
    out0[((size_t)b * CHN + c) * KTOP + j] = x[((size_t)b * CHN + c) * HWSZ + pix];
    out1[((size_t)b * CHN + c) * KTOP + j] = pos[(size_t)c * HWSZ + pix];
}

// ===========================================================================
// Fallback (round-1 fused path) for small workspace.
// ===========================================================================
__global__ __launch_bounds__(256) void fb_fused_conv_kernel(
    const float* __restrict__ x, const float* __restrict__ w1,
    const float* __restrict__ b1, const float* __restrict__ w2,
    const float* __restrict__ b2, float* __restrict__ logits_out,
    int* __restrict__ cls_map, float* __restrict__ prob_map)
{
    __shared__ float xs[16][3][36];
    __shared__ float ys[CHN][36];
    __shared__ float lsf[NCLS][36];

    const int blk = blockIdx.x;
    const int b   = blk >> 9;
    const int rem = blk & 511;
    const int h   = rem >> 2;
    const int w0  = (rem & 3) << 5;
    const int t   = threadIdx.x;
    const int oc  = t;

    float acc[32];
#pragma unroll
    for (int i = 0; i < 32; ++i) acc[i] = 0.f;
    const float* xb = x + (size_t)b * CHN * HWSZ;

    for (int icc = 0; icc < CHN; icc += 16) {
        __syncthreads();
        for (int li = t; li < 16 * 3 * 34; li += 256) {
            int ic  = li / 102;
            int r   = (li % 102) / 34;
            int col = li % 34;
            int gh = h - 1 + r;
            int gw = w0 - 1 + col;
            float v = 0.f;
            if ((unsigned)gh < HH && (unsigned)gw < WW)
                v = xb[(size_t)(icc + ic) * HWSZ + gh * WW + gw];
            xs[ic][r][col] = v;
        }
        __syncthreads();
        const float* wp = w1 + (size_t)oc * (CHN * 9) + (size_t)icc * 9;
#pragma unroll 2
        for (int ic = 0; ic < 16; ++ic) {
            float wk[9];
#pragma unroll
            for (int k = 0; k < 9; ++k) wk[k] = wp[ic * 9 + k];
#pragma unroll
            for (int kh = 0; kh < 3; ++kh) {
                float xr[34];
#pragma unroll
                for (int j = 0; j < 34; ++j) xr[j] = xs[ic][kh][j];
#pragma unroll
                for (int kw = 0; kw < 3; ++kw) {
                    float wv = wk[kh * 3 + kw];
#pragma unroll
                    for (int px = 0; px < 32; ++px)
                        acc[px] = fmaf(wv, xr[px + kw], acc[px]);
                }
            }
        }
    }
    float bias = b1[oc];
#pragma unroll
    for (int px = 0; px < 32; ++px) {
        float v = acc[px] + bias;
        ys[oc][px] = v > 0.f ? v : 0.f;
    }
    __syncthreads();
    if (t < 2 * NCLS) {
        int c   = t % NCLS;
        int ph  = t / NCLS;
        int pxo = ph * 16;
        float acc2[16];
        float bias2 = b2[c];
#pragma unroll
        for (int i = 0; i < 16; ++i) acc2[i] = bias2;
        const float* w2p = w2 + c * CHN;
#pragma unroll 4
        for (int ic = 0; ic < CHN; ++ic) {
            float wv = w2p[ic];
#pragma unroll
            for (int i = 0; i < 16; ++i)
                acc2[i] = fmaf(wv, ys[ic][pxo + i], acc2[i]);
        }
        float* lo = logits_out + ((size_t)b * NCLS + c) * HWSZ + h * WW + w0 + pxo;
#pragma unroll
        for (int i = 0; i < 16; ++i) { lo[i] = acc2[i]; lsf[c][pxo + i] = acc2[i]; }
    }
    __syncthreads();
    if (t < 32) {
        int px = t;
        float m = -1e30f;
#pragma unroll
        for (int c = 0; c < NCLS; ++c) m = fmaxf(m, lsf[c][px]);
        float s = 0.f;
        for (int c = 0; c < NCLS; ++c) s += expf(lsf[c][px] - m);
        float best = -1e30f; int bc = 0;
        for (int c = 0; c < NFG; ++c) {
            float v = lsf[c][px];
            if (v > best) { best = v; bc = c; }
        }
        int off = b * HWSZ + h * WW + w0 + px;
        cls_map[off]  = bc;
        prob_map[off] = expf(best - m) / s;
    }
}

extern "C" void kernel_launch(void* const* d_in, const int* in_sizes, int n_in,
                              void* d_out, int out_size, void* d_ws, size_t ws_size,
                              hipStream_t stream) {
    (void)in_sizes; (void)n_in; (void)out_size;
    const float* x   = (const float*)d_in[0];
    const float* pos = (const float*)d_in[1];
    const float* w1  = (const float*)d_in[2];
    const float* b1  = (const float*)d_in[3];
    const float* w2  = (const float*)d_in[4];
    const float* b2  = (const float*)d_in[5];

    float* out0   = (float*)d_out;                    // [8,256,100]
    float* out1   = out0 + BATCH * CHN * KTOP;        // [8,256,100]
    float* logits = out1 + BATCH * CHN * KTOP;        // [8,81,128,128]

    char* ws = (char*)d_ws;
    const size_t NPX = (size_t)BATCH * HWSZ;          // 131072
    int*   cls_map  = (int*)ws;
    float* prob_map = (float*)(ws + NPX * 4);
    float* score    = (float*)(ws + 2 * NPX * 4);
    int*   idx      = (int*)(ws + 3 * NPX * 4);
    float* w1t      = (float*)(ws + 3 * NPX * 4 + 4096);
    float* w2t      = w1t + 2304 * 256;
    float* y        = w2t + 256 * 128;                // pad 81->128
    size_t need     = (char*)(y + NPX * CHN) - ws;

    if (ws_size >= need) {
        prep_weights<<<2385, 256, 0, stream>>>(w1, w2, w1t, w2t);
        conv3_kernel<<<BATCH * HH * 2, 256, 0, stream>>>(x, w1t, b1, y);
        head_kernel<<<(int)(NPX / 32), 256, 0, stream>>>(
            y, w2t, b2, logits, cls_map, prob_map);
    } else {
        fb_fused_conv_kernel<<<BATCH * HH * 4, 256, 0, stream>>>(
            x, w1, b1, w2, b2, logits, cls_map, prob_map);
    }
    locmax_kernel<<<(int)(NPX / 256), 256, 0, stream>>>(cls_map, prob_map, score);
    topk_kernel<<<BATCH, 256, 0, stream>>>(score, idx);
    gather_kernel<<<BATCH * KTOP, 256, 0, stream>>>(x, pos, idx, out0, out1);
}

// Round 3
// 1503.337 us; speedup vs baseline: 2.9619x; 2.0953x over previous
//
#include <hip/hip_runtime.h>
#include <cmath>

#define BATCH 8
#define CHN 256
#define HH 128
#define WW 128
#define HWSZ (HH*WW)
#define NCLS 81
#define NFG 80
#define KTOP 100
#define EPSV 1e-6f
#define ICCH 32

typedef __attribute__((ext_vector_type(8))) short short8;
typedef __attribute__((ext_vector_type(4))) float f32x4;

__device__ __forceinline__ ushort f2bf(float f) {
    unsigned u = __float_as_uint(f);
    unsigned r = (u + 0x7FFFu + ((u >> 16) & 1u)) >> 16;
    return (ushort)r;
}
__device__ __forceinline__ float bf2f(ushort h) {
    return __uint_as_float(((unsigned)h) << 16);
}

// ===========================================================================
// prep_x: x NCHW fp32 -> xh/xl NHWC bf16 (hi + residual-lo split).
// Block: 32-px tile of one row; LDS transpose, conflict-free phases.
// ===========================================================================
__global__ __launch_bounds__(256) void prep_x(
    const float* __restrict__ x, ushort* __restrict__ xh, ushort* __restrict__ xl)
{
    __shared__ float tile[CHN][33];
    const int blk = blockIdx.x;          // 8*128*4 = 4096
    const int q4  = blk & 3;
    const int h   = (blk >> 2) & 127;
    const int b   = blk >> 9;
    const int w0  = q4 << 5;
    const int t   = threadIdx.x;

    for (int i = 0; i < 32; ++i) {
        int idx = i * 256 + t;
        int c   = idx >> 5;
        int px  = idx & 31;
        tile[c][px] = x[(((size_t)b * CHN + c) * HH + h) * WW + w0 + px];
    }
    __syncthreads();
    for (int i = 0; i < 4; ++i) {
        int idx = i * 256 + t;
        int px  = idx & 31;
        int c8  = idx >> 5;              // 0..31
        short8 hv, lv;
#pragma unroll
        for (int j = 0; j < 8; ++j) {
            float f  = tile[c8 * 8 + j][px];
            ushort hb = f2bf(f);
            ushort lb = f2bf(f - bf2f(hb));
            hv[j] = (short)hb;
            lv[j] = (short)lb;
        }
        size_t addr = ((size_t)b * HWSZ + h * WW + w0 + px) * CHN + c8 * 8;
        *(short8*)(xh + addr) = hv;
        *(short8*)(xl + addr) = lv;
    }
}

// ===========================================================================
// prep_w_mfma: w1 OIHW -> Bsw in MFMA B-frag order
//   Bsw[(tap*8+kt)*16384 + spl*8192 + ntg*512 + lane*8 + j]
//   value = split(w1[oc=ntg*16+(lane&15)][ic=kt*32+(lane>>4)*8+j][tap])
// plus w2t[ic*81+c] for the head.
// ===========================================================================
__global__ __launch_bounds__(256) void prep_w_mfma(
    const float* __restrict__ w1, const float* __restrict__ w2,
    ushort* __restrict__ Bsw, float* __restrict__ w2t)
{
    int i = blockIdx.x * 256 + threadIdx.x;
    if (i < 73728) {                      // 9*8*16*64
        int tap  = i >> 13;
        int rem  = i & 8191;
        int kt   = rem >> 10;
        int rem2 = rem & 1023;
        int ntg  = rem2 >> 6;
        int lane = rem2 & 63;
        int oc   = ntg * 16 + (lane & 15);
        int ic0  = kt * 32 + (lane >> 4) * 8;
        size_t base = (size_t)(tap * 8 + kt) * 16384 + (size_t)ntg * 512 + lane * 8;
#pragma unroll
        for (int j = 0; j < 8; ++j) {
            float w  = w1[(size_t)oc * 2304 + (ic0 + j) * 9 + tap];
            ushort hb = f2bf(w);
            ushort lb = f2bf(w - bf2f(hb));
            Bsw[base + j]        = hb;
            Bsw[base + 8192 + j] = lb;
        }
    } else {
        int j = i - 73728;
        if (j < 256 * NCLS) {
            int ic = j / NCLS, c = j - ic * NCLS;
            w2t[ic * NCLS + c] = w2[c * CHN + ic];
        }
    }
}

// ===========================================================================
// conv3_mfma: implicit-GEMM conv3x3 via mfma_f32_16x16x32_bf16, 3-term
// bf16 split (hi*hi + hi*lo + lo*hi). Block = 128px(row) x 128oc, 4 waves
// of 64x64. No LDS, no barriers: A frags per-lane 16B loads from NHWC,
// B frags coalesced from pre-swizzled Bsw. Writes relu(y) NHWC fp32.
// ===========================================================================
__global__ __launch_bounds__(256, 3) void conv3_mfma_kernel(
    const ushort* __restrict__ xh, const ushort* __restrict__ xl,
    const ushort* __restrict__ Bsw, const float* __restrict__ b1,
    float* __restrict__ y)
{
    const int blk   = blockIdx.x;        // 2048
    const int nhalf = blk & 1;
    const int rowid = blk >> 1;
    const int b     = rowid >> 7;
    const int h     = rowid & 127;
    const int t     = threadIdx.x;
    const int lane  = t & 63;
    const int wv    = t >> 6;
    const int wm    = wv >> 1;
    const int wn    = wv & 1;
    const int l15   = lane & 15;
    const int q     = lane >> 4;

    const short8 zz = {0, 0, 0, 0, 0, 0, 0, 0};
    f32x4 acc[4][4];
#pragma unroll
    for (int i = 0; i < 4; ++i)
#pragma unroll
        for (int j = 0; j < 4; ++j) { f32x4 z = {0.f, 0.f, 0.f, 0.f}; acc[i][j] = z; }

    const int mbase = wm * 64 + l15;
    const int koffq = q * 8;

    for (int kh = 0; kh < 3; ++kh) {
        const int gh = h - 1 + kh;
        if ((unsigned)gh >= (unsigned)HH) continue;   // zero-pad row: skip
        const ushort* xrh = xh + ((size_t)(b * HH + gh) * WW) * CHN;
        const ushort* xrl = xl + ((size_t)(b * HH + gh) * WW) * CHN;
        for (int kw = 0; kw < 3; ++kw) {
            const int tap = kh * 3 + kw;
            const ushort* bb = Bsw + (size_t)(tap * 8) * 16384;
            int pw[4]; bool ok[4];
#pragma unroll
            for (int mt = 0; mt < 4; ++mt) {
                int p = mbase + mt * 16 - 1 + kw;
                ok[mt] = ((unsigned)p < (unsigned)WW);
                pw[mt] = ok[mt] ? p : 0;
            }
            for (int kt = 0; kt < 8; ++kt) {
                short8 ah[4], al[4];
                const int ko = kt * 32 + koffq;
#pragma unroll
                for (int mt = 0; mt < 4; ++mt) {
                    const size_t po = (size_t)pw[mt] * CHN + ko;
                    short8 vh = *(const short8*)(xrh + po);
                    short8 vl = *(const short8*)(xrl + po);
                    if (!ok[mt]) { vh = zz; vl = zz; }
                    ah[mt] = vh; al[mt] = vl;
                }
                const ushort* bk = bb + (size_t)kt * 16384 + lane * 8;
#pragma unroll
                for (int nt = 0; nt < 4; ++nt) {
                    const int ntg = nhalf * 8 + wn * 4 + nt;
                    short8 bh = *(const short8*)(bk + ntg * 512);
                    short8 bl = *(const short8*)(bk + 8192 + ntg * 512);
#pragma unroll
                    for (int mt = 0; mt < 4; ++mt)
                        acc[mt][nt] = __builtin_amdgcn_mfma_f32_16x16x32_bf16(
                            ah[mt], bh, acc[mt][nt], 0, 0, 0);
#pragma unroll
                    for (int mt = 0; mt < 4; ++mt)
                        acc[mt][nt] = __builtin_amdgcn_mfma_f32_16x16x32_bf16(
                            ah[mt], bl, acc[mt][nt], 0, 0, 0);
#pragma unroll
                    for (int mt = 0; mt < 4; ++mt)
                        acc[mt][nt] = __builtin_amdgcn_mfma_f32_16x16x32_bf16(
                            al[mt], bh, acc[mt][nt], 0, 0, 0);
                }
            }
        }
    }

    // epilogue: C/D layout col(oc)=lane&15, row(px)=q*4+r
    const size_t pxbase = (size_t)b * HWSZ + h * WW;
#pragma unroll
    for (int nt = 0; nt < 4; ++nt) {
        const int oc = nhalf * 128 + wn * 64 + nt * 16 + l15;
        const float bias = b1[oc];
#pragma unroll
        for (int mt = 0; mt < 4; ++mt) {
#pragma unroll
            for (int r = 0; r < 4; ++r) {
                const int m = wm * 64 + mt * 16 + q * 4 + r;
                float v = acc[mt][nt][r] + bias;
                y[(pxbase + m) * CHN + oc] = v > 0.f ? v : 0.f;
            }
        }
    }
}

// ===========================================================================
// Fallback fp32 path (round-2, proven): weight transpose + vector conv.
// ===========================================================================
__global__ __launch_bounds__(256) void prep_weights(
    const float* __restrict__ w1, const float* __restrict__ w2,
    float* __restrict__ w1t, float* __restrict__ w2t)
{
    int i = blockIdx.x * 256 + threadIdx.x;
    if (i < 2304 * 256) {
        int ick = i >> 8;
        int oc  = i & 255;
        w1t[ick * 256 + oc] = w1[oc * 2304 + ick];
    } else {
        int j = i - 2304 * 256;
        if (j < 256 * 81) {
            int ic = j / 81, c = j - ic * 81;
            w2t[ic * 81 + c] = w2[c * 256 + ic];
        }
    }
}

__global__ __launch_bounds__(256) void conv3_kernel(
    const float* __restrict__ x, const float* __restrict__ w1t,
    const float* __restrict__ b1, float* __restrict__ y)
{
    __shared__ float xs[ICCH][3][68];
    const int blk  = blockIdx.x;
    const int b    = blk >> 8;
    const int h    = (blk >> 1) & 127;
    const int w0   = (blk & 1) << 6;
    const int t    = threadIdx.x;
    const int lane = t & 63;
    const int pxg  = t >> 6;
    const int colbase = pxg << 4;

    float acc[4][16];
#pragma unroll
    for (int j = 0; j < 4; ++j)
#pragma unroll
        for (int p = 0; p < 16; ++p) acc[j][p] = 0.f;

    const float* xb = x + (size_t)b * CHN * HWSZ;
    for (int icc = 0; icc < CHN; icc += ICCH) {
        __syncthreads();
        for (int li = t; li < ICCH * 3 * 66; li += 256) {
            int ic  = li / 198;
            int rr  = li - ic * 198;
            int r   = rr / 66;
            int col = rr - r * 66;
            int gh = h - 1 + r;
            int gw = w0 - 1 + col;
            float v = 0.f;
            if ((unsigned)gh < HH && (unsigned)gw < WW)
                v = xb[(size_t)(icc + ic) * HWSZ + gh * WW + gw];
            xs[ic][r][col] = v;
        }
        __syncthreads();
        for (int ic = 0; ic < ICCH; ++ic) {
            const float* wrow = w1t + (size_t)(icc + ic) * 9 * 256 + lane;
#pragma unroll
            for (int kh = 0; kh < 3; ++kh) {
                float xr[18];
#pragma unroll
                for (int u = 0; u < 18; ++u) xr[u] = xs[ic][kh][colbase + u];
#pragma unroll
                for (int j = 0; j < 4; ++j) {
                    float wv0 = wrow[(kh * 3 + 0) * 256 + j * 64];
                    float wv1 = wrow[(kh * 3 + 1) * 256 + j * 64];
                    float wv2 = wrow[(kh * 3 + 2) * 256 + j * 64];
#pragma unroll
                    for (int p = 0; p < 16; ++p) {
                        float a = acc[j][p];
                        a = fmaf(wv0, xr[p],     a);
                        a = fmaf(wv1, xr[p + 1], a);
                        a = fmaf(wv2, xr[p + 2], a);
                        acc[j][p] = a;
                    }
                }
            }
        }
    }
    size_t pxflat = (size_t)b * HWSZ + h * WW + w0 + colbase;
#pragma unroll
    for (int j = 0; j < 4; ++j) {
        float bias = b1[j * 64 + lane];
#pragma unroll
        for (int p = 0; p < 16; ++p) {
            float v = acc[j][p] + bias;
            y[(pxflat + p) * CHN + j * 64 + lane] = v > 0.f ? v : 0.f;
        }
    }
}

// ===========================================================================
// head: 1x1 conv (256->81) + bias + softmax + foreground argmax. (proven)
// ===========================================================================
__global__ __launch_bounds__(256) void head_kernel(
    const float* __restrict__ y, const float* __restrict__ w2t,
    const float* __restrict__ b2, float* __restrict__ logits_out,
    int* __restrict__ cls_map, float* __restrict__ prob_map)
{
    __shared__ float ls[32][NCLS];
    const int blk = blockIdx.x;
    const int t   = threadIdx.x;
    const size_t px0 = (size_t)blk * 32;

    if (t < 2 * NCLS) {
        int g = t / NCLS;
        int c = t - g * NCLS;
        float acc[16];
        float bias = b2[c];
#pragma unroll
        for (int p = 0; p < 16; ++p) acc[p] = bias;
        const float* yb = y + (px0 + g * 16) * CHN;
        for (int ic4 = 0; ic4 < 64; ++ic4) {
            float wv[4];
#pragma unroll
            for (int u = 0; u < 4; ++u) wv[u] = w2t[(ic4 * 4 + u) * NCLS + c];
#pragma unroll
            for (int p = 0; p < 16; ++p) {
                const float4 yv = *(const float4*)(yb + (size_t)p * CHN + ic4 * 4);
                float a = acc[p];
                a = fmaf(wv[0], yv.x, a);
                a = fmaf(wv[1], yv.y, a);
                a = fmaf(wv[2], yv.z, a);
                a = fmaf(wv[3], yv.w, a);
                acc[p] = a;
            }
        }
        int bb = (int)(px0 >> 14);
        int hw = (int)(px0 & (HWSZ - 1)) + g * 16;
        float* lo = logits_out + ((size_t)bb * NCLS + c) * HWSZ + hw;
#pragma unroll
        for (int p = 0; p < 16; ++p) { lo[p] = acc[p]; ls[g * 16 + p][c] = acc[p]; }
    }
    __syncthreads();

    if (t < 32) {
        float m = -1e30f;
#pragma unroll
        for (int c = 0; c < NCLS; ++c) m = fmaxf(m, ls[t][c]);
        float s = 0.f;
        for (int c = 0; c < NCLS; ++c) s += expf(ls[t][c] - m);
        float best = -1e30f; int bc = 0;
        for (int c = 0; c < NFG; ++c) {
            float v = ls[t][c];
            if (v > best) { best = v; bc = c; }
        }
        cls_map[px0 + t]  = bc;
        prob_map[px0 + t] = expf(best - m) / s;
    }
}

// ===========================================================================
// locmax (proven)
// ===========================================================================
__global__ __launch_bounds__(256) void locmax_kernel(
    const int* __restrict__ cls_map, const float* __restrict__ prob_map,
    float* __restrict__ score)
{
    int i = blockIdx.x * 256 + threadIdx.x;
    int b = i >> 14;
    int p = i & (HWSZ - 1);
    int h = p >> 7, w = p & 127;
    int mycls = cls_map[i];
    float myp = prob_map[i];
    bool lm = (myp >= EPSV);
#pragma unroll
    for (int dh = -1; dh <= 1; ++dh)
#pragma unroll
        for (int dw = -1; dw <= 1; ++dw) {
            if (dh == 0 && dw == 0) continue;
            int nh = h + dh, nw = w + dw;
            if ((unsigned)nh < HH && (unsigned)nw < WW) {
                int ni = b * HWSZ + nh * WW + nw;
                if (cls_map[ni] == mycls && myp < prob_map[ni]) lm = false;
            }
        }
    score[i] = myp + (lm ? 1.f : 0.f);
}

// ===========================================================================
// topk: same extract-max algorithm, widened to 1024 threads (16-elem segs).
// ===========================================================================
__global__ __launch_bounds__(1024) void topk_kernel(
    float* __restrict__ score, int* __restrict__ idx_out)
{
    __shared__ unsigned long long candl[1024];
    __shared__ unsigned long long wmax[16];
    __shared__ unsigned long long bestsh;
    const int b = blockIdx.x;
    const int t = threadIdx.x;
    float* sc = score + b * HWSZ;

    unsigned long long lmax = 0;
    for (int i = 0; i < 16; ++i) {
        int p = t + (i << 10);
        unsigned int fb = __float_as_uint(sc[p]);
        unsigned long long k =
            ((unsigned long long)fb << 32) | (unsigned int)(~p);
        if (k > lmax) lmax = k;
    }
    candl[t] = lmax;
    __syncthreads();

    for (int it = 0; it < KTOP; ++it) {
        unsigned long long v = candl[t];
#pragma unroll
        for (int off = 32; off > 0; off >>= 1) {
            unsigned long long o = __shfl_down(v, off);
            if (o > v) v = o;
        }
        if ((t & 63) == 0) wmax[t >> 6] = v;
        __syncthreads();
        if (t == 0) {
            unsigned long long bb = wmax[0];
            for (int wv = 1; wv < 16; ++wv) if (wmax[wv] > bb) bb = wmax[wv];
            bestsh = bb;
            int pix = (int)(~(unsigned int)(bb & 0xFFFFFFFFull)) & (HWSZ - 1);
            idx_out[b * KTOP + it] = pix;
        }
        __syncthreads();
        unsigned long long bb = bestsh;
        int pix = (int)(~(unsigned int)(bb & 0xFFFFFFFFull)) & (HWSZ - 1);
        int owner = pix & 1023;
        if (t == owner) {
            sc[pix] = 0.f;
            unsigned long long nm = 0;
            for (int i = 0; i < 16; ++i) {
                int p = t + (i << 10);
                unsigned int fb = __float_as_uint(sc[p]);
                unsigned long long k =
                    ((unsigned long long)fb << 32) | (unsigned int)(~p);
                if (k > nm) nm = k;
            }
            candl[t] = nm;
        }
        __syncthreads();
    }
}

// ===========================================================================
// gather (proven)
// ===========================================================================
__global__ __launch_bounds__(256) void gather_kernel(
    const float* __restrict__ x, const float* __restrict__ pos,
    const int* __restrict__ idx, float* __restrict__ out0,
    float* __restrict__ out1)
{
    int blk = blockIdx.x;
    int b = blk / KTOP;
    int j = blk - b * KTOP;
    int c = threadIdx.x;
    int pix = idx[b * KTOP + j];
    out0[((size_t)b * CHN + c) * KTOP + j] = x[((size_t)b * CHN + c) * HWSZ + pix];
    out1[((size_t)b * CHN + c) * KTOP + j] = pos[(size_t)c * HWSZ + pix];
}

extern "C" void kernel_launch(void* const* d_in, const int* in_sizes, int n_in,
                              void* d_out, int out_size, void* d_ws, size_t ws_size,
                              hipStream_t stream) {
    (void)in_sizes; (void)n_in; (void)out_size;
    const float* x   = (const float*)d_in[0];
    const float* pos = (const float*)d_in[1];
    const float* w1  = (const float*)d_in[2];
    const float* b1  = (const float*)d_in[3];
    const float* w2  = (const float*)d_in[4];
    const float* b2  = (const float*)d_in[5];

    float* out0   = (float*)d_out;                    // [8,256,100]
    float* out1   = out0 + BATCH * CHN * KTOP;        // [8,256,100]
    float* logits = out1 + BATCH * CHN * KTOP;        // [8,81,128,128]

    char* ws = (char*)d_ws;
    const size_t NPX = (size_t)BATCH * HWSZ;          // 131072

    // --- MFMA-path workspace layout ---
    size_t off = 0;
    int*    cls_map  = (int*)(ws + off);   off += NPX * 4;
    float*  prob_map = (float*)(ws + off); off += NPX * 4;
    float*  score    = (float*)(ws + off); off += NPX * 4;
    int*    idx      = (int*)(ws + off);   off += 4096;
    float*  w2t      = (float*)(ws + off); off += (size_t)256 * 128 * 4;
    ushort* Bsw      = (ushort*)(ws + off); off += (size_t)9 * 8 * 16384 * 2;
    ushort* xh       = (ushort*)(ws + off); off += NPX * CHN * 2;
    ushort* xl       = (ushort*)(ws + off); off += NPX * CHN * 2;
    float*  y        = (float*)(ws + off);  off += NPX * CHN * 4;
    const size_t need_mfma = off;

    if (ws_size >= need_mfma) {
        prep_x<<<4096, 256, 0, stream>>>(x, xh, xl);
        prep_w_mfma<<<369, 256, 0, stream>>>(w1, w2, Bsw, w2t);
        conv3_mfma_kernel<<<2048, 256, 0, stream>>>(xh, xl, Bsw, b1, y);
        head_kernel<<<(int)(NPX / 32), 256, 0, stream>>>(
            y, w2t, b2, logits, cls_map, prob_map);
    } else {
        // fallback: round-2 fp32 layout
        float* fw1t = (float*)(ws + 3 * NPX * 4 + 4096);
        float* fw2t = fw1t + 2304 * 256;
        float* fy   = fw2t + 256 * 128;
        prep_weights<<<2385, 256, 0, stream>>>(w1, w2, fw1t, fw2t);
        conv3_kernel<<<BATCH * HH * 2, 256, 0, stream>>>(x, fw1t, b1, fy);
        head_kernel<<<(int)(NPX / 32), 256, 0, stream>>>(
            fy, fw2t, b2, logits, cls_map, prob_map);
    }
    locmax_kernel<<<(int)(NPX / 256), 256, 0, stream>>>(cls_map, prob_map, score);
    topk_kernel<<<BATCH, 1024, 0, stream>>>(score, idx);
    gather_kernel<<<BATCH * KTOP, 256, 0, stream>>>(x, pos, idx, out0, out1);
}

// Round 4
// 779.266 us; speedup vs baseline: 5.7140x; 1.9292x over previous
//
#include <hip/hip_runtime.h>
#include <cmath>

#define BATCH 8
#define CHN 256
#define HH 128
#define WW 128
#define HWSZ (HH*WW)
#define NCLS 81
#define NFG 80
#define KTOP 100
#define EPSV 1e-6f

typedef __attribute__((ext_vector_type(8))) short short8;
typedef __attribute__((ext_vector_type(4))) float f32x4;

__device__ __forceinline__ ushort f2bf(float f) {
    unsigned u = __float_as_uint(f);
    return (ushort)((u + 0x7FFFu + ((u >> 16) & 1u)) >> 16);
}
__device__ __forceinline__ float bf2f(ushort h) {
    return __uint_as_float(((unsigned)h) << 16);
}

// ===========================================================================
// prep_x: x NCHW fp32 -> xh/xl NHWC bf16 (hi + residual-lo). LDS transpose;
// phase-2 lanes write consecutive 16B channel chunks (contiguous 512B/px).
// ===========================================================================
__global__ __launch_bounds__(256) void prep_x(
    const float* __restrict__ x, ushort* __restrict__ xh, ushort* __restrict__ xl)
{
    __shared__ float tile[32][CHN + 1];    // [px][c]
    const int blk = blockIdx.x;            // 4096 = 8*128*4
    const int q4 = blk & 3, h = (blk >> 2) & 127, b = blk >> 9;
    const int w0 = q4 << 5;
    const int t = threadIdx.x;
    const int px1 = t & 31, cq = t >> 5;

    const float* xb = x + ((size_t)b * CHN) * HWSZ + h * WW + w0;
#pragma unroll 4
    for (int i = 0; i < 32; ++i) {
        int c = i * 8 + cq;
        tile[px1][c] = xb[(size_t)c * HWSZ + px1];
    }
    __syncthreads();
    for (int i = 0; i < 4; ++i) {
        int u = i * 256 + t;
        int c8 = u & 31, px = u >> 5;
        short8 hv, lv;
#pragma unroll
        for (int j = 0; j < 8; ++j) {
            float f = tile[px][c8 * 8 + j];
            ushort hb = f2bf(f);
            hv[j] = (short)hb;
            lv[j] = (short)f2bf(f - bf2f(hb));
        }
        size_t addr = ((size_t)b * HWSZ + h * WW + w0 + px) * CHN + c8 * 8;
        *(short8*)(xh + addr) = hv;
        *(short8*)(xl + addr) = lv;
    }
}

// ===========================================================================
// prep_w: w1 -> Bsw (conv B-frags, hi/lo), w2 -> w2sw (head B-frags, 96-oc pad)
// Bsw[(tap*8+kt)*16384 + spl*8192 + ntg*512 + lane*8 + j]
// w2sw[(kt*12 + spl*6 + ntg)*512 + lane*8 + j]
// ===========================================================================
__global__ __launch_bounds__(256) void prep_w(
    const float* __restrict__ w1, const float* __restrict__ w2,
    ushort* __restrict__ Bsw, ushort* __restrict__ w2sw)
{
    int i = blockIdx.x * 256 + threadIdx.x;     // 312*256 = 79872
    if (i < 73728) {                            // 9*8*16*64
        int tap  = i >> 13;
        int rem  = i & 8191;
        int kt   = rem >> 10;
        int rem2 = rem & 1023;
        int ntg  = rem2 >> 6;
        int lane = rem2 & 63;
        int oc   = ntg * 16 + (lane & 15);
        int ic0  = kt * 32 + (lane >> 4) * 8;
        size_t base = (size_t)(tap * 8 + kt) * 16384 + (size_t)ntg * 512 + lane * 8;
#pragma unroll
        for (int j = 0; j < 8; ++j) {
            float w  = w1[(size_t)oc * 2304 + (ic0 + j) * 9 + tap];
            ushort hb = f2bf(w);
            Bsw[base + j]        = hb;
            Bsw[base + 8192 + j] = f2bf(w - bf2f(hb));
        }
    } else {
        int j2 = i - 73728;                     // < 6144 = 8*2*6*64
        int kt   = j2 / 768;
        int rem  = j2 - kt * 768;
        int spl  = rem / 384;
        int rem2 = rem - spl * 384;
        int ntg  = rem2 >> 6;
        int lane = rem2 & 63;
        int oc   = ntg * 16 + (lane & 15);
        int ic0  = kt * 32 + (lane >> 4) * 8;
        size_t base = (size_t)(kt * 12 + spl * 6 + ntg) * 512 + lane * 8;
#pragma unroll
        for (int j = 0; j < 8; ++j) {
            float w = (oc < NCLS) ? w2[(size_t)oc * CHN + ic0 + j] : 0.f;
            ushort hb = f2bf(w);
            w2sw[base + j] = spl ? f2bf(w - bf2f(hb)) : hb;
        }
    }
}

// ===========================================================================
// conv3_mfma2: block = one row (128 px) x 256 oc, 4 waves (128px x 64oc each).
// A staged in LDS per 32-ch chunk: [kh][pxs][32ch] -> staging writes and
// frag ds_read_b128 both fully contiguous. B frags coalesced from Bsw (L2).
// 3-term bf16 split. Writes relu(y) NHWC fp32.
// ===========================================================================
__global__ __launch_bounds__(256, 2) void conv3_mfma2(
    const ushort* __restrict__ xh, const ushort* __restrict__ xl,
    const ushort* __restrict__ Bsw, const float* __restrict__ b1,
    float* __restrict__ y)
{
    __shared__ ushort Ah[3][132 * 32];   // [kh][pxs*32 + ch], 25344 B
    __shared__ ushort Al[3][132 * 32];

    const int blk  = blockIdx.x;         // 1024 = 8*128
    const int b    = blk >> 7;
    const int h    = blk & 127;
    const int t    = threadIdx.x;
    const int lane = t & 63;
    const int w    = t >> 6;             // wave: oc base = w*64
    const int l15  = lane & 15;
    const int q    = lane >> 4;

    const short8 zz = {0, 0, 0, 0, 0, 0, 0, 0};
    f32x4 acc[8][4];
#pragma unroll
    for (int i = 0; i < 8; ++i)
#pragma unroll
        for (int j = 0; j < 4; ++j) { f32x4 z = {0.f, 0.f, 0.f, 0.f}; acc[i][j] = z; }

    for (int kt = 0; kt < 8; ++kt) {
        __syncthreads();
        // stage: 3120 16B units = 2 arr x 3 kh x 130 pxs x 4 q
        for (int u = t; u < 3120; u += 256) {
            int arr = u >= 1560;
            int v   = arr ? u - 1560 : u;
            int kh  = v / 520;
            int r   = v - kh * 520;
            int pxs = r >> 2;
            int qq  = r & 3;
            int gh = h - 1 + kh, gw = pxs - 1;
            short8 val = zz;
            if ((unsigned)gh < (unsigned)HH && (unsigned)gw < (unsigned)WW) {
                const ushort* src = (arr ? xl : xh) +
                    (((size_t)(b * HH + gh) * WW + gw) * CHN + kt * 32 + qq * 8);
                val = *(const short8*)src;
            }
            ushort* dst = (arr ? Al[kh] : Ah[kh]) + pxs * 32 + qq * 8;
            *(short8*)dst = val;
        }
        __syncthreads();

#pragma unroll
        for (int tap = 0; tap < 9; ++tap) {
            const int kh = tap / 3, kw = tap % 3;
            const ushort* bk = Bsw + (size_t)(tap * 8 + kt) * 16384 + lane * 8;
            short8 bh[4], bl[4];
#pragma unroll
            for (int nt = 0; nt < 4; ++nt) {
                bh[nt] = *(const short8*)(bk + (w * 4 + nt) * 512);
                bl[nt] = *(const short8*)(bk + 8192 + (w * 4 + nt) * 512);
            }
#pragma unroll
            for (int mth = 0; mth < 8; mth += 4) {
                short8 ahf[4], alf[4];
#pragma unroll
                for (int mm = 0; mm < 4; ++mm) {
                    int pxs = (mth + mm) * 16 + l15 + kw;
                    ahf[mm] = *(const short8*)(Ah[kh] + pxs * 32 + q * 8);
                    alf[mm] = *(const short8*)(Al[kh] + pxs * 32 + q * 8);
                }
#pragma unroll
                for (int nt = 0; nt < 4; ++nt) {
#pragma unroll
                    for (int mm = 0; mm < 4; ++mm)
                        acc[mth + mm][nt] = __builtin_amdgcn_mfma_f32_16x16x32_bf16(
                            ahf[mm], bh[nt], acc[mth + mm][nt], 0, 0, 0);
#pragma unroll
                    for (int mm = 0; mm < 4; ++mm)
                        acc[mth + mm][nt] = __builtin_amdgcn_mfma_f32_16x16x32_bf16(
                            ahf[mm], bl[nt], acc[mth + mm][nt], 0, 0, 0);
#pragma unroll
                    for (int mm = 0; mm < 4; ++mm)
                        acc[mth + mm][nt] = __builtin_amdgcn_mfma_f32_16x16x32_bf16(
                            alf[mm], bh[nt], acc[mth + mm][nt], 0, 0, 0);
                }
            }
        }
    }

    // epilogue: px = mt*16 + q*4 + r, oc = w*64 + nt*16 + l15
    const size_t rowbase = (size_t)b * HWSZ + h * WW;
#pragma unroll
    for (int nt = 0; nt < 4; ++nt) {
        const int oc = w * 64 + nt * 16 + l15;
        const float bias = b1[oc];
#pragma unroll
        for (int mt = 0; mt < 8; ++mt) {
#pragma unroll
            for (int r = 0; r < 4; ++r) {
                const int px = mt * 16 + q * 4 + r;
                float v = acc[mt][nt][r] + bias;
                y[(rowbase + px) * CHN + oc] = v > 0.f ? v : 0.f;
            }
        }
    }
}

// ===========================================================================
// head_mfma: 1x1 conv (256->81, pad 96) via MFMA with on-the-fly bf16 split
// of y, + bias + softmax + argmax. Block = one row (128 px), wave = 32 px.
// ===========================================================================
__global__ __launch_bounds__(256) void head_mfma(
    const float* __restrict__ y, const ushort* __restrict__ w2sw,
    const float* __restrict__ b2, float* __restrict__ logits_out,
    int* __restrict__ cls_map, float* __restrict__ prob_map)
{
    __shared__ float ls[128][97];        // [px][oc], pad 97 (conflict-free)
    const int blk = blockIdx.x;          // 1024
    const int b = blk >> 7, h = blk & 127;
    const int t = threadIdx.x, lane = t & 63, wm = t >> 6;
    const int l15 = lane & 15, q = lane >> 4;

    f32x4 acc[2][6];
#pragma unroll
    for (int i = 0; i < 2; ++i)
#pragma unroll
        for (int j = 0; j < 6; ++j) { f32x4 z = {0.f, 0.f, 0.f, 0.f}; acc[i][j] = z; }

    const size_t rowbase = (size_t)b * HWSZ + h * WW;

    for (int kt = 0; kt < 8; ++kt) {
        short8 ah[2], al[2];
#pragma unroll
        for (int mt = 0; mt < 2; ++mt) {
            const float* src = y + (rowbase + wm * 32 + mt * 16 + l15) * CHN + kt * 32 + q * 8;
            float4 f0 = *(const float4*)src;
            float4 f1 = *(const float4*)(src + 4);
            float fv[8] = {f0.x, f0.y, f0.z, f0.w, f1.x, f1.y, f1.z, f1.w};
#pragma unroll
            for (int j = 0; j < 8; ++j) {
                ushort hb = f2bf(fv[j]);
                ah[mt][j] = (short)hb;
                al[mt][j] = (short)f2bf(fv[j] - bf2f(hb));
            }
        }
        const ushort* bk = w2sw + (size_t)kt * 12 * 512 + lane * 8;
#pragma unroll
        for (int nt = 0; nt < 6; ++nt) {
            short8 bh = *(const short8*)(bk + nt * 512);
            short8 bl = *(const short8*)(bk + (6 + nt) * 512);
#pragma unroll
            for (int mt = 0; mt < 2; ++mt) {
                acc[mt][nt] = __builtin_amdgcn_mfma_f32_16x16x32_bf16(ah[mt], bh, acc[mt][nt], 0, 0, 0);
                acc[mt][nt] = __builtin_amdgcn_mfma_f32_16x16x32_bf16(ah[mt], bl, acc[mt][nt], 0, 0, 0);
                acc[mt][nt] = __builtin_amdgcn_mfma_f32_16x16x32_bf16(al[mt], bh, acc[mt][nt], 0, 0, 0);
            }
        }
    }

    // bias + stash logits to LDS
#pragma unroll
    for (int nt = 0; nt < 6; ++nt) {
        const int oc = nt * 16 + l15;
        const float bias = (oc < NCLS) ? b2[oc] : 0.f;
#pragma unroll
        for (int mt = 0; mt < 2; ++mt) {
#pragma unroll
            for (int r = 0; r < 4; ++r) {
                const int px = wm * 32 + mt * 16 + q * 4 + r;
                ls[px][oc] = acc[mt][nt][r] + bias;
            }
        }
    }
    __syncthreads();

    // logits out (NCHW), coalesced
    for (int i = t; i < NCLS * 128; i += 256) {
        int c = i >> 7, px = i & 127;
        logits_out[((size_t)b * NCLS + c) * HWSZ + h * WW + px] = ls[px][c];
    }

    // softmax + first-occurrence foreground argmax
    if (t < 128) {
        const int px = t;
        float m = -1e30f;
#pragma unroll
        for (int c = 0; c < NCLS; ++c) m = fmaxf(m, ls[px][c]);
        float s = 0.f;
        for (int c = 0; c < NCLS; ++c) s += expf(ls[px][c] - m);
        float best = -1e30f; int bc = 0;
        for (int c = 0; c < NFG; ++c) {
            float v = ls[px][c];
            if (v > best) { best = v; bc = c; }   // strict > keeps first index
        }
        cls_map[rowbase + px]  = bc;
        prob_map[rowbase + px] = expf(best - m) / s;
    }
}

// ===========================================================================
// locmax (proven)
// ===========================================================================
__global__ __launch_bounds__(256) void locmax_kernel(
    const int* __restrict__ cls_map, const float* __restrict__ prob_map,
    float* __restrict__ score)
{
    int i = blockIdx.x * 256 + threadIdx.x;
    int b = i >> 14;
    int p = i & (HWSZ - 1);
    int h = p >> 7, w = p & 127;
    int mycls = cls_map[i];
    float myp = prob_map[i];
    bool lm = (myp >= EPSV);
#pragma unroll
    for (int dh = -1; dh <= 1; ++dh)
#pragma unroll
        for (int dw = -1; dw <= 1; ++dw) {
            if (dh == 0 && dw == 0) continue;
            int nh = h + dh, nw = w + dw;
            if ((unsigned)nh < HH && (unsigned)nw < WW) {
                int ni = b * HWSZ + nh * WW + nw;
                if (cls_map[ni] == mycls && myp < prob_map[ni]) lm = false;
            }
        }
    score[i] = myp + (lm ? 1.f : 0.f);
}

// ===========================================================================
// topk: 4-level byte-histogram radix select + rank scatter.
// jax.lax.top_k semantics: value desc, tie -> lower index (u64 (key<<32)|~p).
// Scores strictly positive -> float bits order-isomorphic.
// ===========================================================================
__global__ __launch_bounds__(1024) void topk_kernel(
    const float* __restrict__ score, int* __restrict__ idx_out)
{
    __shared__ unsigned int hist[256];
    __shared__ unsigned long long cand[2048];   // [0..127]: >K, [128..]: ==K
    __shared__ unsigned int sprefix, sneed, scntA, scntB;
    const int b = blockIdx.x;
    const int t = threadIdx.x;
    const float* sc = score + b * HWSZ;

    unsigned keys[16];
#pragma unroll
    for (int i = 0; i < 16; ++i)
        keys[i] = __float_as_uint(sc[t + (i << 10)]);

    if (t == 0) { sneed = KTOP; sprefix = 0; scntA = 0; scntB = 0; }

    for (int lvl = 0; lvl < 4; ++lvl) {
        const int shift = 24 - 8 * lvl;
        if (t < 256) hist[t] = 0;
        __syncthreads();
        const unsigned pref = sprefix;
#pragma unroll
        for (int i = 0; i < 16; ++i) {
            unsigned k = keys[i];
            bool match = (lvl == 0) || ((k >> (shift + 8)) == pref);
            if (match) atomicAdd(&hist[(k >> shift) & 255u], 1u);
        }
        __syncthreads();
        if (t == 0) {
            unsigned needv = sneed, c = 0; int bsel = 0;
            for (int j = 255; j >= 0; --j) {
                unsigned nc = c + hist[j];
                if (nc >= needv) { bsel = j; break; }
                c = nc;
            }
            sprefix = (pref << 8) | (unsigned)bsel;
            sneed = needv - c;
        }
        __syncthreads();
    }

    const unsigned K = sprefix;
#pragma unroll
    for (int i = 0; i < 16; ++i) {
        unsigned k = keys[i];
        int p = t + (i << 10);
        if (k > K) {
            unsigned pos = atomicAdd(&scntA, 1u);   // <= 99 guaranteed
            cand[pos] = ((unsigned long long)k << 32) | (unsigned)(~p);
        } else if (k == K) {
            unsigned pos = atomicAdd(&scntB, 1u);
            if (pos < 1920u)
                cand[128 + pos] = ((unsigned long long)k << 32) | (unsigned)(~p);
        }
    }
    __syncthreads();
    const int cA = (int)scntA;
    const int cB = (int)(scntB < 1920u ? scntB : 1920u);
    const int Ctot = cA + cB;
    for (int ti = t; ti < Ctot; ti += 1024) {
        unsigned long long my = cand[ti < cA ? ti : 128 + (ti - cA)];
        int rank = 0;
        for (int j = 0; j < Ctot; ++j) {
            unsigned long long o = cand[j < cA ? j : 128 + (j - cA)];
            rank += (o > my) ? 1 : 0;
        }
        if (rank < KTOP)
            idx_out[b * KTOP + rank] =
                (int)(~(unsigned)(my & 0xFFFFFFFFull)) & (HWSZ - 1);
    }
}

// ===========================================================================
// gather (proven)
// ===========================================================================
__global__ __launch_bounds__(256) void gather_kernel(
    const float* __restrict__ x, const float* __restrict__ pos,
    const int* __restrict__ idx, float* __restrict__ out0,
    float* __restrict__ out1)
{
    int blk = blockIdx.x;
    int b = blk / KTOP;
    int j = blk - b * KTOP;
    int c = threadIdx.x;
    int pix = idx[b * KTOP + j];
    out0[((size_t)b * CHN + c) * KTOP + j] = x[((size_t)b * CHN + c) * HWSZ + pix];
    out1[((size_t)b * CHN + c) * KTOP + j] = pos[(size_t)c * HWSZ + pix];
}

extern "C" void kernel_launch(void* const* d_in, const int* in_sizes, int n_in,
                              void* d_out, int out_size, void* d_ws, size_t ws_size,
                              hipStream_t stream) {
    (void)in_sizes; (void)n_in; (void)out_size; (void)ws_size;
    const float* x   = (const float*)d_in[0];
    const float* pos = (const float*)d_in[1];
    const float* w1  = (const float*)d_in[2];
    const float* b1  = (const float*)d_in[3];
    const float* w2  = (const float*)d_in[4];
    const float* b2  = (const float*)d_in[5];

    float* out0   = (float*)d_out;                    // [8,256,100]
    float* out1   = out0 + BATCH * CHN * KTOP;        // [8,256,100]
    float* logits = out1 + BATCH * CHN * KTOP;        // [8,81,128,128]

    char* ws = (char*)d_ws;
    const size_t NPX = (size_t)BATCH * HWSZ;          // 131072

    size_t off = 0;
    int*    cls_map  = (int*)(ws + off);    off += NPX * 4;
    float*  prob_map = (float*)(ws + off);  off += NPX * 4;
    float*  score    = (float*)(ws + off);  off += NPX * 4;
    int*    idx      = (int*)(ws + off);    off += 4096;
    ushort* w2sw     = (ushort*)(ws + off); off += (size_t)8 * 12 * 512 * 2;
    ushort* Bsw      = (ushort*)(ws + off); off += (size_t)9 * 8 * 16384 * 2;
    ushort* xh       = (ushort*)(ws + off); off += NPX * CHN * 2;
    ushort* xl       = (ushort*)(ws + off); off += NPX * CHN * 2;
    float*  y        = (float*)(ws + off);  off += NPX * CHN * 4;

    prep_x<<<4096, 256, 0, stream>>>(x, xh, xl);
    prep_w<<<312, 256, 0, stream>>>(w1, w2, Bsw, w2sw);
    conv3_mfma2<<<1024, 256, 0, stream>>>(xh, xl, Bsw, b1, y);
    head_mfma<<<1024, 256, 0, stream>>>(y, w2sw, b2, logits, cls_map, prob_map);
    locmax_kernel<<<(int)(NPX / 256), 256, 0, stream>>>(cls_map, prob_map, score);
    topk_kernel<<<BATCH, 1024, 0, stream>>>(score, idx);
    gather_kernel<<<BATCH * KTOP, 256, 0, stream>>>(x, pos, idx, out0, out1);
}